// Round 3
// baseline (590.093 us; speedup 1.0000x reference)
//
#include <hip/hip_runtime.h>

typedef unsigned short u16;
typedef __attribute__((ext_vector_type(8))) short bf16x8;
typedef __attribute__((ext_vector_type(4))) short bf16x4;
typedef __attribute__((ext_vector_type(4))) float f32x4;

#define MFMA16(a, b, c) __builtin_amdgcn_mfma_f32_16x16x32_bf16(a, b, c, 0, 0, 0)

__device__ __forceinline__ u16 f2bf(float x) {
    unsigned u = __float_as_uint(x);
    return (u16)((u + 0x7fffu + ((u >> 16) & 1u)) >> 16);
}
__device__ __forceinline__ u16 f2bf_fast(float x) {  // round-half-up (P matrix only)
    return (u16)((__float_as_uint(x) + 0x8000u) >> 16);
}

// ---------------------------------------------------------------------------
// fp32 -> bf16 flat cast. n must be a multiple of 8*256.
// ---------------------------------------------------------------------------
__global__ __launch_bounds__(256) void castk(const float* __restrict__ src, u16* __restrict__ dst) {
    const int i = (blockIdx.x * 256 + threadIdx.x) * 8;
    float4 a = *(const float4*)(src + i);
    float4 b = *(const float4*)(src + i + 4);
    bf16x8 v;
    v[0] = (short)f2bf(a.x); v[1] = (short)f2bf(a.y);
    v[2] = (short)f2bf(a.z); v[3] = (short)f2bf(a.w);
    v[4] = (short)f2bf(b.x); v[5] = (short)f2bf(b.y);
    v[6] = (short)f2bf(b.z); v[7] = (short)f2bf(b.w);
    *(bf16x8*)(dst + i) = v;
}

// ---------------------------------------------------------------------------
// fp32 src[r][c] -> bf16 dst[c][r], 64x64 LDS tiles. grid R/64*C/64, block 256
// ---------------------------------------------------------------------------
__global__ __launch_bounds__(256) void tkern(const float* __restrict__ src, u16* __restrict__ dst,
                                             int R, int C) {
    const int tC = C >> 6;
    const int tr = (blockIdx.x / tC) << 6;
    const int tc = (blockIdx.x % tC) << 6;
    __shared__ u16 ls[64 * 68];
    const int tid = threadIdx.x;
#pragma unroll
    for (int rep = 0; rep < 2; ++rep) {
        const int f = tid * 8 + rep * 2048;
        const int r = f >> 6, c = f & 63;
        float4 a = *(const float4*)(src + (size_t)(tr + r) * C + tc + c);
        float4 b = *(const float4*)(src + (size_t)(tr + r) * C + tc + c + 4);
        bf16x4 lo, hi;
        lo[0] = (short)f2bf(a.x); lo[1] = (short)f2bf(a.y);
        lo[2] = (short)f2bf(a.z); lo[3] = (short)f2bf(a.w);
        hi[0] = (short)f2bf(b.x); hi[1] = (short)f2bf(b.y);
        hi[2] = (short)f2bf(b.z); hi[3] = (short)f2bf(b.w);
        *(bf16x4*)&ls[r * 68 + c] = lo;
        *(bf16x4*)&ls[r * 68 + c + 4] = hi;
    }
    __syncthreads();
#pragma unroll
    for (int rep = 0; rep < 2; ++rep) {
        const int f = tid * 8 + rep * 2048;
        const int rn = f >> 6, ck = f & 63;
        bf16x8 v;
#pragma unroll
        for (int j = 0; j < 8; ++j) v[j] = (short)ls[(ck + j) * 68 + rn];
        *(bf16x8*)(dst + (size_t)(tc + rn) * R + tr + ck) = v;
    }
}

// ---------------------------------------------------------------------------
// GEMM: C[m][n] = sum_k A[m][k] * Bt[n][k] + bias[n].  M=8192, K=1024, bf16.
// MODE 0: N=3072, scatter to Q(scaled)[BH][T][D], K[BH][T][D], V^T[BH][D][T].
// MODE 1: N=1024, fp32 store to Of[M][N].
// ---------------------------------------------------------------------------
template <int MODE>
__global__ __launch_bounds__(256) void gemm_k(const u16* __restrict__ A, const u16* __restrict__ Bt,
                                              const float* __restrict__ bias,
                                              u16* __restrict__ Qo, u16* __restrict__ Ko,
                                              u16* __restrict__ Vo, float* __restrict__ Of) {
    constexpr int Kd = 1024;
    const int tid = threadIdx.x;
    const int lane = tid & 63, wave = tid >> 6;
    const int wm = wave >> 1, wn = wave & 1;
    const int lr = lane & 15, lg = lane >> 4;
    const int mt = blockIdx.x & 63;
    const int nt = blockIdx.x >> 6;
    const int mbase = mt << 7, nbase = nt << 7;
    __shared__ u16 As[128 * 32];
    __shared__ u16 Bs[128 * 32];
    f32x4 acc[4][4];
#pragma unroll
    for (int i = 0; i < 4; ++i)
#pragma unroll
        for (int j = 0; j < 4; ++j) acc[i][j] = {0.f, 0.f, 0.f, 0.f};

    for (int kb = 0; kb < Kd; kb += 32) {
        __syncthreads();
#pragma unroll
        for (int rep = 0; rep < 2; ++rep) {
            const int f = tid * 8 + rep * 2048;
            const int r = f >> 5, c = f & 31;
            __builtin_amdgcn_global_load_lds(
                (const __attribute__((address_space(1))) void*)(A + (size_t)(mbase + r) * Kd + kb + c),
                (__attribute__((address_space(3))) void*)(As + f), 16, 0, 0);
            __builtin_amdgcn_global_load_lds(
                (const __attribute__((address_space(1))) void*)(Bt + (size_t)(nbase + r) * Kd + kb + c),
                (__attribute__((address_space(3))) void*)(Bs + f), 16, 0, 0);
        }
        __syncthreads();
        bf16x8 af[4], bfr[4];
#pragma unroll
        for (int i = 0; i < 4; ++i)
            af[i] = *(const bf16x8*)&As[(wm * 64 + i * 16 + lr) * 32 + lg * 8];
#pragma unroll
        for (int j = 0; j < 4; ++j)
            bfr[j] = *(const bf16x8*)&Bs[(wn * 64 + j * 16 + lr) * 32 + lg * 8];
#pragma unroll
        for (int i = 0; i < 4; ++i)
#pragma unroll
            for (int j = 0; j < 4; ++j) acc[i][j] = MFMA16(af[i], bfr[j], acc[i][j]);
    }

    const float QSCALE = 0.1803368801111137f;  // 0.125 * log2(e), folded into Q
#pragma unroll
    for (int j = 0; j < 4; ++j) {
        const int n = nbase + wn * 64 + j * 16 + lr;
        const float bj = bias[n];
        if (MODE == 0) {
            const int three = n >> 10;
            const int h = (n >> 6) & 15;
            const int d = n & 63;
#pragma unroll
            for (int i = 0; i < 4; ++i) {
#pragma unroll
                for (int r = 0; r < 4; ++r) {
                    const int m = mbase + wm * 64 + i * 16 + lg * 4 + r;
                    const int b = m >> 11, t = m & 2047;
                    const int bh = (b << 4) + h;
                    const float val = acc[i][j][r] + bj;
                    if (three == 0)
                        Qo[(((size_t)bh << 11) + t) * 64 + d] = f2bf(val * QSCALE);
                    else if (three == 1)
                        Ko[(((size_t)bh << 11) + t) * 64 + d] = f2bf(val);
                    else
                        Vo[(((size_t)bh << 6) + d) * 2048 + t] = f2bf(val);
                }
            }
        } else {
#pragma unroll
            for (int i = 0; i < 4; ++i) {
#pragma unroll
                for (int r = 0; r < 4; ++r) {
                    const int m = mbase + wm * 64 + i * 16 + lg * 4 + r;
                    Of[((size_t)m << 10) + n] = acc[i][j][r] + bj;
                }
            }
        }
    }
}

// ---------------------------------------------------------------------------
// Causal flash attention, barrier-free, register-resident K/V fragments.
// Q,K: [BH][T][D] bf16 (Q pre-scaled), Vt: [BH][D][T] bf16, Aout: [B][T][C].
// grid (16, B*H), block 128 (2 waves). Block bx pairs q-tiles qb_hi=16+bx,
// qb_lo=15-bx (perfect balance). Each wave owns 32 q of hi + 32 q of lo
// (4 subtiles) -- r0 geometry (133us), restored after the 4-wave split
// regressed (same kt trip count, half the compute per K/V load -> 2x exposed
// load latency).
// NEW vs r0:
//  (a) K/V register fragments are DOUBLE-BUFFERED with a ping-pong 2x-unrolled
//      kt loop: the 16 global loads for kt+1 issue before the 4 subtile
//      processes of kt (~2000cy of MFMA/VALU hides ~200-900cy load latency).
//      All buffer indices are static (runtime-indexed ext_vector arrays spill
//      to scratch).
//  (b) P scratch split by subtile parity (Ps[wave][st&1]) so consecutive
//      subtile chains don't serialize on the same LDS buffer alias.
// ---------------------------------------------------------------------------
__global__ __launch_bounds__(128, 2) void flash_attn(const u16* __restrict__ Q, const u16* __restrict__ Kg,
                                                     const u16* __restrict__ Vt, u16* __restrict__ Aout) {
    const int tid = threadIdx.x;
    const int lane = tid & 63, wave = tid >> 6;  // wave 0..1
    const int lr = lane & 15, lg = lane >> 4;
    const int bx = blockIdx.x;   // 0..15
    const int bh = blockIdx.y;   // 0..63
    const int b = bh >> 4, h = bh & 15;
    const size_t base = (size_t)bh << 17;  // bh * 2048 * 64

    const int qb_hi = 16 + bx;
    const int qb_lo = 15 - bx;

    __shared__ u16 Ps[2][2][16 * 72];  // [wave][st&1] P scratch

    // subtile q-bases: 0,1 = hi halves; 2,3 = lo halves
    int qbase[4];
    qbase[0] = qb_hi * 64 + wave * 32;
    qbase[1] = qbase[0] + 16;
    qbase[2] = qb_lo * 64 + wave * 32;
    qbase[3] = qbase[2] + 16;

    bf16x8 qf[4][2];
#pragma unroll
    for (int st = 0; st < 4; ++st) {
        const u16* p = Q + base + (size_t)(qbase[st] + lr) * 64;
        qf[st][0] = *(const bf16x8*)(p + lg * 8);
        qf[st][1] = *(const bf16x8*)(p + 32 + lg * 8);
    }

    f32x4 o[4][4];
#pragma unroll
    for (int st = 0; st < 4; ++st)
#pragma unroll
        for (int dt = 0; dt < 4; ++dt) o[st][dt] = {0.f, 0.f, 0.f, 0.f};
    float m_[4] = {-INFINITY, -INFINITY, -INFINITY, -INFINITY};
    float l_[4] = {0.f, 0.f, 0.f, 0.f};

    // K A-frag: row kt*64 + rt*16 + lr, cols lg*8(+32). V^T B-frag: row dt*16+lr,
    // cols kt*64 + lg*8(+32). Both q-independent -> load once per kt.
    const u16* Kbase = Kg + base + (size_t)lr * 64 + lg * 8;
    const u16* Vbase = Vt + base + (size_t)lr * 2048 + lg * 8;

    auto loadkv = [&](bf16x8 (&kf)[4][2], bf16x8 (&vf)[4][2], int kt) {
        const u16* kp = Kbase + (size_t)kt * 4096;
#pragma unroll
        for (int rt = 0; rt < 4; ++rt) {
            kf[rt][0] = *(const bf16x8*)(kp + rt * 1024);
            kf[rt][1] = *(const bf16x8*)(kp + rt * 1024 + 32);
        }
        const u16* vp = Vbase + kt * 64;
#pragma unroll
        for (int dt = 0; dt < 4; ++dt) {
            vf[dt][0] = *(const bf16x8*)(vp + dt * 32768);
            vf[dt][1] = *(const bf16x8*)(vp + dt * 32768 + 32);
        }
    };

    auto process = [&](const bf16x8 (&kf)[4][2], const bf16x8 (&vf)[4][2], int kt, int st,
                       bool diag) {
        // S^T[kv][q] = K * Q^T  (kv = kt*64 + rt*16 + lg*4 + reg, q = lr)
        f32x4 s[4];
#pragma unroll
        for (int rt = 0; rt < 4; ++rt) {
            f32x4 z = {0.f, 0.f, 0.f, 0.f};
            z = MFMA16(kf[rt][0], qf[st][0], z);
            z = MFMA16(kf[rt][1], qf[st][1], z);
            s[rt] = z;
        }
        if (diag) {
            const int q_glob = qbase[st] + lr;
#pragma unroll
            for (int rt = 0; rt < 4; ++rt)
#pragma unroll
                for (int r = 0; r < 4; ++r) {
                    const int kv = kt * 64 + rt * 16 + lg * 4 + r;
                    if (kv > q_glob) s[rt][r] = -INFINITY;
                }
        }
        float rmax = -INFINITY;
#pragma unroll
        for (int rt = 0; rt < 4; ++rt)
#pragma unroll
            for (int r = 0; r < 4; ++r) rmax = fmaxf(rmax, s[rt][r]);
        rmax = fmaxf(rmax, __shfl_xor(rmax, 16));
        rmax = fmaxf(rmax, __shfl_xor(rmax, 32));
        const float m_new = fmaxf(m_[st], rmax);
        const float alpha = exp2f(m_[st] - m_new);
        float rsum = 0.f;
#pragma unroll
        for (int rt = 0; rt < 4; ++rt)
#pragma unroll
            for (int r = 0; r < 4; ++r) {
                const float p = exp2f(s[rt][r] - m_new);
                s[rt][r] = p;
                rsum += p;
            }
        rsum += __shfl_xor(rsum, 16);
        rsum += __shfl_xor(rsum, 32);
        l_[st] = l_[st] * alpha + rsum;
        m_[st] = m_new;

        // P (C-layout) -> LDS -> A-layout frags
        u16* psb = &Ps[wave][st & 1][0];
#pragma unroll
        for (int rt = 0; rt < 4; ++rt) {
            bf16x4 pk;
#pragma unroll
            for (int r = 0; r < 4; ++r) pk[r] = (short)f2bf_fast(s[rt][r]);
            *(bf16x4*)&psb[lr * 72 + rt * 16 + lg * 4] = pk;
        }
        float aq[4];
#pragma unroll
        for (int r = 0; r < 4; ++r) aq[r] = __shfl(alpha, (lane & 48) + lg * 4 + r);
#pragma unroll
        for (int dt = 0; dt < 4; ++dt)
#pragma unroll
            for (int r = 0; r < 4; ++r) o[st][dt][r] *= aq[r];

        const bf16x8 pf0 = *(const bf16x8*)&psb[lr * 72 + lg * 8];
        const bf16x8 pf1 = *(const bf16x8*)&psb[lr * 72 + 32 + lg * 8];
#pragma unroll
        for (int dt = 0; dt < 4; ++dt) {
            o[st][dt] = MFMA16(pf0, vf[dt][0], o[st][dt]);
            o[st][dt] = MFMA16(pf1, vf[dt][1], o[st][dt]);
        }
    };

    auto step = [&](const bf16x8 (&kf)[4][2], const bf16x8 (&vf)[4][2], int kt) {
        process(kf, vf, kt, 0, kt == qb_hi);
        process(kf, vf, kt, 1, kt == qb_hi);
        if (kt <= qb_lo) {
            process(kf, vf, kt, 2, kt == qb_lo);
            process(kf, vf, kt, 3, kt == qb_lo);
        }
    };

    // ping-pong double-buffered kt loop: loads for kt+1 issue before step(kt)
    bf16x8 kfA[4][2], vfA[4][2], kfB[4][2], vfB[4][2];
    loadkv(kfA, vfA, 0);
    int kt = 0;
    for (;;) {
        if (kt < qb_hi) loadkv(kfB, vfB, kt + 1);
        step(kfA, vfA, kt);
        if (++kt > qb_hi) break;
        if (kt < qb_hi) loadkv(kfA, vfA, kt + 1);
        step(kfB, vfB, kt);
        if (++kt > qb_hi) break;
    }

#pragma unroll
    for (int st = 0; st < 4; ++st) {
        const float linv = 1.f / l_[st];
        float lq[4];
#pragma unroll
        for (int r = 0; r < 4; ++r) lq[r] = __shfl(linv, (lane & 48) + lg * 4 + r);
#pragma unroll
        for (int dt = 0; dt < 4; ++dt)
#pragma unroll
            for (int r = 0; r < 4; ++r) {
                const int t = qbase[st] + lg * 4 + r;
                Aout[(((size_t)(b << 11) + t) << 10) + h * 64 + dt * 16 + lr] =
                    f2bf(o[st][dt][r] * lq[r]);
            }
    }
}

// ---------------------------------------------------------------------------
extern "C" void kernel_launch(void* const* d_in, const int* in_sizes, int n_in,
                              void* d_out, int out_size, void* d_ws, size_t ws_size,
                              hipStream_t stream) {
    (void)in_sizes; (void)n_in; (void)out_size; (void)ws_size;
    const float* x    = (const float*)d_in[0];
    const float* Wqkv = (const float*)d_in[2];
    const float* bqkv = (const float*)d_in[3];
    const float* Wout = (const float*)d_in[4];
    const float* bout = (const float*)d_in[5];
    float* out = (float*)d_out;

    char* ws = (char*)d_ws;
    u16* WqkvT = (u16*)(ws);                    //  6 MB: [3072][1024] bf16
    u16* WoutT = (u16*)(ws + 6291456);          //  2 MB: [1024][1024] bf16
    u16* xb    = (u16*)(ws + 8388608);          // 16 MB: [8192][1024] bf16
    u16* Qb    = (u16*)(ws + 25165824);         // 16 MB: [BH][T][D]
    u16* Kb    = (u16*)(ws + 41943040);         // 16 MB: [BH][T][D]
    u16* Vtb   = (u16*)(ws + 58720256);         // 16 MB: [BH][D][T]
    u16* Ab    = (u16*)(ws + 75497472);         // 16 MB: [B][T][C]

    castk<<<dim3(4096), 256, 0, stream>>>(x, xb);
    tkern<<<dim3(16 * 48), 256, 0, stream>>>(Wqkv, WqkvT, 1024, 3072);
    tkern<<<dim3(16 * 16), 256, 0, stream>>>(Wout, WoutT, 1024, 1024);
    gemm_k<0><<<dim3(64 * 24), 256, 0, stream>>>(xb, WqkvT, bqkv, Qb, Kb, Vtb, nullptr);
    flash_attn<<<dim3(16, 64), 128, 0, stream>>>(Qb, Kb, Vtb, Ab);
    gemm_k<1><<<dim3(64 * 8), 256, 0, stream>>>(Ab, WoutT, bout, nullptr, nullptr, nullptr, out);
}

// Round 4
// 351.481 us; speedup vs baseline: 1.6789x; 1.6789x over previous
//
#include <hip/hip_runtime.h>

typedef unsigned short u16;
typedef __attribute__((ext_vector_type(8))) short bf16x8;
typedef __attribute__((ext_vector_type(4))) short bf16x4;
typedef __attribute__((ext_vector_type(4))) float f32x4;

#define MFMA16(a, b, c) __builtin_amdgcn_mfma_f32_16x16x32_bf16(a, b, c, 0, 0, 0)

__device__ __forceinline__ u16 f2bf(float x) {
    unsigned u = __float_as_uint(x);
    return (u16)((u + 0x7fffu + ((u >> 16) & 1u)) >> 16);
}
__device__ __forceinline__ u16 f2bf_fast(float x) {  // round-half-up (P matrix only)
    return (u16)((__float_as_uint(x) + 0x8000u) >> 16);
}

// ---------------------------------------------------------------------------
// fp32 -> bf16 flat cast. n must be a multiple of 8*256.
// ---------------------------------------------------------------------------
__global__ __launch_bounds__(256) void castk(const float* __restrict__ src, u16* __restrict__ dst) {
    const int i = (blockIdx.x * 256 + threadIdx.x) * 8;
    float4 a = *(const float4*)(src + i);
    float4 b = *(const float4*)(src + i + 4);
    bf16x8 v;
    v[0] = (short)f2bf(a.x); v[1] = (short)f2bf(a.y);
    v[2] = (short)f2bf(a.z); v[3] = (short)f2bf(a.w);
    v[4] = (short)f2bf(b.x); v[5] = (short)f2bf(b.y);
    v[6] = (short)f2bf(b.z); v[7] = (short)f2bf(b.w);
    *(bf16x8*)(dst + i) = v;
}

// ---------------------------------------------------------------------------
// fp32 src[r][c] -> bf16 dst[c][r], 64x64 LDS tiles. grid R/64*C/64, block 256
// ---------------------------------------------------------------------------
__global__ __launch_bounds__(256) void tkern(const float* __restrict__ src, u16* __restrict__ dst,
                                             int R, int C) {
    const int tC = C >> 6;
    const int tr = (blockIdx.x / tC) << 6;
    const int tc = (blockIdx.x % tC) << 6;
    __shared__ u16 ls[64 * 68];
    const int tid = threadIdx.x;
#pragma unroll
    for (int rep = 0; rep < 2; ++rep) {
        const int f = tid * 8 + rep * 2048;
        const int r = f >> 6, c = f & 63;
        float4 a = *(const float4*)(src + (size_t)(tr + r) * C + tc + c);
        float4 b = *(const float4*)(src + (size_t)(tr + r) * C + tc + c + 4);
        bf16x4 lo, hi;
        lo[0] = (short)f2bf(a.x); lo[1] = (short)f2bf(a.y);
        lo[2] = (short)f2bf(a.z); lo[3] = (short)f2bf(a.w);
        hi[0] = (short)f2bf(b.x); hi[1] = (short)f2bf(b.y);
        hi[2] = (short)f2bf(b.z); hi[3] = (short)f2bf(b.w);
        *(bf16x4*)&ls[r * 68 + c] = lo;
        *(bf16x4*)&ls[r * 68 + c + 4] = hi;
    }
    __syncthreads();
#pragma unroll
    for (int rep = 0; rep < 2; ++rep) {
        const int f = tid * 8 + rep * 2048;
        const int rn = f >> 6, ck = f & 63;
        bf16x8 v;
#pragma unroll
        for (int j = 0; j < 8; ++j) v[j] = (short)ls[(ck + j) * 68 + rn];
        *(bf16x8*)(dst + (size_t)(tc + rn) * R + tr + ck) = v;
    }
}

// ---------------------------------------------------------------------------
// GEMM: C[m][n] = sum_k A[m][k] * Bt[n][k] + bias[n].  M=8192, K=1024, bf16.
// MODE 0: N=3072, scatter to Q(scaled)[BH][T][D], K[BH][T][D], V^T[BH][D][T].
// MODE 1: N=1024, fp32 store to Of[M][N].
// ---------------------------------------------------------------------------
template <int MODE>
__global__ __launch_bounds__(256) void gemm_k(const u16* __restrict__ A, const u16* __restrict__ Bt,
                                              const float* __restrict__ bias,
                                              u16* __restrict__ Qo, u16* __restrict__ Ko,
                                              u16* __restrict__ Vo, float* __restrict__ Of) {
    constexpr int Kd = 1024;
    const int tid = threadIdx.x;
    const int lane = tid & 63, wave = tid >> 6;
    const int wm = wave >> 1, wn = wave & 1;
    const int lr = lane & 15, lg = lane >> 4;
    const int mt = blockIdx.x & 63;
    const int nt = blockIdx.x >> 6;
    const int mbase = mt << 7, nbase = nt << 7;
    __shared__ u16 As[128 * 32];
    __shared__ u16 Bs[128 * 32];
    f32x4 acc[4][4];
#pragma unroll
    for (int i = 0; i < 4; ++i)
#pragma unroll
        for (int j = 0; j < 4; ++j) acc[i][j] = {0.f, 0.f, 0.f, 0.f};

    for (int kb = 0; kb < Kd; kb += 32) {
        __syncthreads();
#pragma unroll
        for (int rep = 0; rep < 2; ++rep) {
            const int f = tid * 8 + rep * 2048;
            const int r = f >> 5, c = f & 31;
            __builtin_amdgcn_global_load_lds(
                (const __attribute__((address_space(1))) void*)(A + (size_t)(mbase + r) * Kd + kb + c),
                (__attribute__((address_space(3))) void*)(As + f), 16, 0, 0);
            __builtin_amdgcn_global_load_lds(
                (const __attribute__((address_space(1))) void*)(Bt + (size_t)(nbase + r) * Kd + kb + c),
                (__attribute__((address_space(3))) void*)(Bs + f), 16, 0, 0);
        }
        __syncthreads();
        bf16x8 af[4], bfr[4];
#pragma unroll
        for (int i = 0; i < 4; ++i)
            af[i] = *(const bf16x8*)&As[(wm * 64 + i * 16 + lr) * 32 + lg * 8];
#pragma unroll
        for (int j = 0; j < 4; ++j)
            bfr[j] = *(const bf16x8*)&Bs[(wn * 64 + j * 16 + lr) * 32 + lg * 8];
#pragma unroll
        for (int i = 0; i < 4; ++i)
#pragma unroll
            for (int j = 0; j < 4; ++j) acc[i][j] = MFMA16(af[i], bfr[j], acc[i][j]);
    }

    const float QSCALE = 0.1803368801111137f;  // 0.125 * log2(e), folded into Q
#pragma unroll
    for (int j = 0; j < 4; ++j) {
        const int n = nbase + wn * 64 + j * 16 + lr;
        const float bj = bias[n];
        if (MODE == 0) {
            const int three = n >> 10;
            const int h = (n >> 6) & 15;
            const int d = n & 63;
#pragma unroll
            for (int i = 0; i < 4; ++i) {
#pragma unroll
                for (int r = 0; r < 4; ++r) {
                    const int m = mbase + wm * 64 + i * 16 + lg * 4 + r;
                    const int b = m >> 11, t = m & 2047;
                    const int bh = (b << 4) + h;
                    const float val = acc[i][j][r] + bj;
                    if (three == 0)
                        Qo[(((size_t)bh << 11) + t) * 64 + d] = f2bf(val * QSCALE);
                    else if (three == 1)
                        Ko[(((size_t)bh << 11) + t) * 64 + d] = f2bf(val);
                    else
                        Vo[(((size_t)bh << 6) + d) * 2048 + t] = f2bf(val);
                }
            }
        } else {
#pragma unroll
            for (int i = 0; i < 4; ++i) {
#pragma unroll
                for (int r = 0; r < 4; ++r) {
                    const int m = mbase + wm * 64 + i * 16 + lg * 4 + r;
                    Of[((size_t)m << 10) + n] = acc[i][j][r] + bj;
                }
            }
        }
    }
}

// ---------------------------------------------------------------------------
// Causal flash attention, barrier-free, register-resident K/V fragments.
// Q,K: [BH][T][D] bf16 (Q pre-scaled), Vt: [BH][D][T] bf16, Aout: [B][T][C].
// grid (16, B*H), block 128 (2 waves). Block bx pairs q-tiles qb_hi=16+bx,
// qb_lo=15-bx (perfect balance). Each wave owns 32 q of hi + 32 q of lo
// (4 subtiles). K/V register fragments are DOUBLE-BUFFERED with a ping-pong
// 2x-unrolled kt loop: the 16 global loads for kt+1 issue before the 4
// subtile processes of kt.
// REGISTER BUDGET NOTE: __launch_bounds__ 2nd arg acts as a hard VGPR cap in
// hipcc: (256,4) capped at 64 VGPR (r1), (128,2) capped at 128 VGPR (r3) ->
// both spilled catastrophically (WRITE_SIZE 199/517 MB). This kernel needs
// ~190 VGPR for the double buffer. Grid (1024 blocks x 2 waves = 2/SIMD)
// already limits occupancy, and 2 waves/SIMD allows 256 VGPR -> the extra
// registers are free. So: NO second launch_bounds argument.
// ---------------------------------------------------------------------------
__global__ __launch_bounds__(128) void flash_attn(const u16* __restrict__ Q, const u16* __restrict__ Kg,
                                                  const u16* __restrict__ Vt, u16* __restrict__ Aout) {
    const int tid = threadIdx.x;
    const int lane = tid & 63, wave = tid >> 6;  // wave 0..1
    const int lr = lane & 15, lg = lane >> 4;
    const int bx = blockIdx.x;   // 0..15
    const int bh = blockIdx.y;   // 0..63
    const int b = bh >> 4, h = bh & 15;
    const size_t base = (size_t)bh << 17;  // bh * 2048 * 64

    const int qb_hi = 16 + bx;
    const int qb_lo = 15 - bx;

    __shared__ u16 Ps[2][2][16 * 72];  // [wave][st&1] P scratch

    // subtile q-bases: 0,1 = hi halves; 2,3 = lo halves
    int qbase[4];
    qbase[0] = qb_hi * 64 + wave * 32;
    qbase[1] = qbase[0] + 16;
    qbase[2] = qb_lo * 64 + wave * 32;
    qbase[3] = qbase[2] + 16;

    bf16x8 qf[4][2];
#pragma unroll
    for (int st = 0; st < 4; ++st) {
        const u16* p = Q + base + (size_t)(qbase[st] + lr) * 64;
        qf[st][0] = *(const bf16x8*)(p + lg * 8);
        qf[st][1] = *(const bf16x8*)(p + 32 + lg * 8);
    }

    f32x4 o[4][4];
#pragma unroll
    for (int st = 0; st < 4; ++st)
#pragma unroll
        for (int dt = 0; dt < 4; ++dt) o[st][dt] = {0.f, 0.f, 0.f, 0.f};
    float m_[4] = {-INFINITY, -INFINITY, -INFINITY, -INFINITY};
    float l_[4] = {0.f, 0.f, 0.f, 0.f};

    // K A-frag: row kt*64 + rt*16 + lr, cols lg*8(+32). V^T B-frag: row dt*16+lr,
    // cols kt*64 + lg*8(+32). Both q-independent -> load once per kt.
    const u16* Kbase = Kg + base + (size_t)lr * 64 + lg * 8;
    const u16* Vbase = Vt + base + (size_t)lr * 2048 + lg * 8;

    auto loadkv = [&](bf16x8 (&kf)[4][2], bf16x8 (&vf)[4][2], int kt) {
        const u16* kp = Kbase + (size_t)kt * 4096;
#pragma unroll
        for (int rt = 0; rt < 4; ++rt) {
            kf[rt][0] = *(const bf16x8*)(kp + rt * 1024);
            kf[rt][1] = *(const bf16x8*)(kp + rt * 1024 + 32);
        }
        const u16* vp = Vbase + kt * 64;
#pragma unroll
        for (int dt = 0; dt < 4; ++dt) {
            vf[dt][0] = *(const bf16x8*)(vp + dt * 32768);
            vf[dt][1] = *(const bf16x8*)(vp + dt * 32768 + 32);
        }
    };

    auto process = [&](const bf16x8 (&kf)[4][2], const bf16x8 (&vf)[4][2], int kt, int st,
                       bool diag) {
        // S^T[kv][q] = K * Q^T  (kv = kt*64 + rt*16 + lg*4 + reg, q = lr)
        f32x4 s[4];
#pragma unroll
        for (int rt = 0; rt < 4; ++rt) {
            f32x4 z = {0.f, 0.f, 0.f, 0.f};
            z = MFMA16(kf[rt][0], qf[st][0], z);
            z = MFMA16(kf[rt][1], qf[st][1], z);
            s[rt] = z;
        }
        if (diag) {
            const int q_glob = qbase[st] + lr;
#pragma unroll
            for (int rt = 0; rt < 4; ++rt)
#pragma unroll
                for (int r = 0; r < 4; ++r) {
                    const int kv = kt * 64 + rt * 16 + lg * 4 + r;
                    if (kv > q_glob) s[rt][r] = -INFINITY;
                }
        }
        float rmax = -INFINITY;
#pragma unroll
        for (int rt = 0; rt < 4; ++rt)
#pragma unroll
            for (int r = 0; r < 4; ++r) rmax = fmaxf(rmax, s[rt][r]);
        rmax = fmaxf(rmax, __shfl_xor(rmax, 16));
        rmax = fmaxf(rmax, __shfl_xor(rmax, 32));
        const float m_new = fmaxf(m_[st], rmax);
        const float alpha = exp2f(m_[st] - m_new);
        float rsum = 0.f;
#pragma unroll
        for (int rt = 0; rt < 4; ++rt)
#pragma unroll
            for (int r = 0; r < 4; ++r) {
                const float p = exp2f(s[rt][r] - m_new);
                s[rt][r] = p;
                rsum += p;
            }
        rsum += __shfl_xor(rsum, 16);
        rsum += __shfl_xor(rsum, 32);
        l_[st] = l_[st] * alpha + rsum;
        m_[st] = m_new;

        // P (C-layout) -> LDS -> A-layout frags
        u16* psb = &Ps[wave][st & 1][0];
#pragma unroll
        for (int rt = 0; rt < 4; ++rt) {
            bf16x4 pk;
#pragma unroll
            for (int r = 0; r < 4; ++r) pk[r] = (short)f2bf_fast(s[rt][r]);
            *(bf16x4*)&psb[lr * 72 + rt * 16 + lg * 4] = pk;
        }
        float aq[4];
#pragma unroll
        for (int r = 0; r < 4; ++r) aq[r] = __shfl(alpha, (lane & 48) + lg * 4 + r);
#pragma unroll
        for (int dt = 0; dt < 4; ++dt)
#pragma unroll
            for (int r = 0; r < 4; ++r) o[st][dt][r] *= aq[r];

        const bf16x8 pf0 = *(const bf16x8*)&psb[lr * 72 + lg * 8];
        const bf16x8 pf1 = *(const bf16x8*)&psb[lr * 72 + 32 + lg * 8];
#pragma unroll
        for (int dt = 0; dt < 4; ++dt) {
            o[st][dt] = MFMA16(pf0, vf[dt][0], o[st][dt]);
            o[st][dt] = MFMA16(pf1, vf[dt][1], o[st][dt]);
        }
    };

    auto step = [&](const bf16x8 (&kf)[4][2], const bf16x8 (&vf)[4][2], int kt) {
        process(kf, vf, kt, 0, kt == qb_hi);
        process(kf, vf, kt, 1, kt == qb_hi);
        if (kt <= qb_lo) {
            process(kf, vf, kt, 2, kt == qb_lo);
            process(kf, vf, kt, 3, kt == qb_lo);
        }
    };

    // ping-pong double-buffered kt loop: loads for kt+1 issue before step(kt)
    bf16x8 kfA[4][2], vfA[4][2], kfB[4][2], vfB[4][2];
    loadkv(kfA, vfA, 0);
    int kt = 0;
    for (;;) {
        if (kt < qb_hi) loadkv(kfB, vfB, kt + 1);
        step(kfA, vfA, kt);
        if (++kt > qb_hi) break;
        if (kt < qb_hi) loadkv(kfA, vfA, kt + 1);
        step(kfB, vfB, kt);
        if (++kt > qb_hi) break;
    }

#pragma unroll
    for (int st = 0; st < 4; ++st) {
        const float linv = 1.f / l_[st];
        float lq[4];
#pragma unroll
        for (int r = 0; r < 4; ++r) lq[r] = __shfl(linv, (lane & 48) + lg * 4 + r);
#pragma unroll
        for (int dt = 0; dt < 4; ++dt)
#pragma unroll
            for (int r = 0; r < 4; ++r) {
                const int t = qbase[st] + lg * 4 + r;
                Aout[(((size_t)(b << 11) + t) << 10) + h * 64 + dt * 16 + lr] =
                    f2bf(o[st][dt][r] * lq[r]);
            }
    }
}

// ---------------------------------------------------------------------------
extern "C" void kernel_launch(void* const* d_in, const int* in_sizes, int n_in,
                              void* d_out, int out_size, void* d_ws, size_t ws_size,
                              hipStream_t stream) {
    (void)in_sizes; (void)n_in; (void)out_size; (void)ws_size;
    const float* x    = (const float*)d_in[0];
    const float* Wqkv = (const float*)d_in[2];
    const float* bqkv = (const float*)d_in[3];
    const float* Wout = (const float*)d_in[4];
    const float* bout = (const float*)d_in[5];
    float* out = (float*)d_out;

    char* ws = (char*)d_ws;
    u16* WqkvT = (u16*)(ws);                    //  6 MB: [3072][1024] bf16
    u16* WoutT = (u16*)(ws + 6291456);          //  2 MB: [1024][1024] bf16
    u16* xb    = (u16*)(ws + 8388608);          // 16 MB: [8192][1024] bf16
    u16* Qb    = (u16*)(ws + 25165824);         // 16 MB: [BH][T][D]
    u16* Kb    = (u16*)(ws + 41943040);         // 16 MB: [BH][T][D]
    u16* Vtb   = (u16*)(ws + 58720256);         // 16 MB: [BH][D][T]
    u16* Ab    = (u16*)(ws + 75497472);         // 16 MB: [B][T][C]

    castk<<<dim3(4096), 256, 0, stream>>>(x, xb);
    tkern<<<dim3(16 * 48), 256, 0, stream>>>(Wqkv, WqkvT, 1024, 3072);
    tkern<<<dim3(16 * 16), 256, 0, stream>>>(Wout, WoutT, 1024, 1024);
    gemm_k<0><<<dim3(64 * 24), 256, 0, stream>>>(xb, WqkvT, bqkv, Qb, Kb, Vtb, nullptr);
    flash_attn<<<dim3(16, 64), 128, 0, stream>>>(Qb, Kb, Vtb, Ab);
    gemm_k<1><<<dim3(64 * 8), 256, 0, stream>>>(Ab, WoutT, bout, nullptr, nullptr, nullptr, out);
}

// Round 5
// 329.099 us; speedup vs baseline: 1.7931x; 1.0680x over previous
//
#include <hip/hip_runtime.h>

typedef unsigned short u16;
typedef __attribute__((ext_vector_type(8))) short bf16x8;
typedef __attribute__((ext_vector_type(4))) short bf16x4;
typedef __attribute__((ext_vector_type(4))) float f32x4;

#define MFMA16(a, b, c) __builtin_amdgcn_mfma_f32_16x16x32_bf16(a, b, c, 0, 0, 0)

__device__ __forceinline__ u16 f2bf(float x) {
    unsigned u = __float_as_uint(x);
    return (u16)((u + 0x7fffu + ((u >> 16) & 1u)) >> 16);
}
__device__ __forceinline__ u16 f2bf_fast(float x) {  // round-half-up (P matrix only)
    return (u16)((__float_as_uint(x) + 0x8000u) >> 16);
}

// ---------------------------------------------------------------------------
// fp32 -> bf16 flat cast. n must be a multiple of 8*256.
// ---------------------------------------------------------------------------
__global__ __launch_bounds__(256) void castk(const float* __restrict__ src, u16* __restrict__ dst) {
    const int i = (blockIdx.x * 256 + threadIdx.x) * 8;
    float4 a = *(const float4*)(src + i);
    float4 b = *(const float4*)(src + i + 4);
    bf16x8 v;
    v[0] = (short)f2bf(a.x); v[1] = (short)f2bf(a.y);
    v[2] = (short)f2bf(a.z); v[3] = (short)f2bf(a.w);
    v[4] = (short)f2bf(b.x); v[5] = (short)f2bf(b.y);
    v[6] = (short)f2bf(b.z); v[7] = (short)f2bf(b.w);
    *(bf16x8*)(dst + i) = v;
}

// ---------------------------------------------------------------------------
// fp32 src[r][c] -> bf16 dst[c][r], 64x64 LDS tiles. grid R/64*C/64, block 256
// ---------------------------------------------------------------------------
__global__ __launch_bounds__(256) void tkern(const float* __restrict__ src, u16* __restrict__ dst,
                                             int R, int C) {
    const int tC = C >> 6;
    const int tr = (blockIdx.x / tC) << 6;
    const int tc = (blockIdx.x % tC) << 6;
    __shared__ u16 ls[64 * 68];
    const int tid = threadIdx.x;
#pragma unroll
    for (int rep = 0; rep < 2; ++rep) {
        const int f = tid * 8 + rep * 2048;
        const int r = f >> 6, c = f & 63;
        float4 a = *(const float4*)(src + (size_t)(tr + r) * C + tc + c);
        float4 b = *(const float4*)(src + (size_t)(tr + r) * C + tc + c + 4);
        bf16x4 lo, hi;
        lo[0] = (short)f2bf(a.x); lo[1] = (short)f2bf(a.y);
        lo[2] = (short)f2bf(a.z); lo[3] = (short)f2bf(a.w);
        hi[0] = (short)f2bf(b.x); hi[1] = (short)f2bf(b.y);
        hi[2] = (short)f2bf(b.z); hi[3] = (short)f2bf(b.w);
        *(bf16x4*)&ls[r * 68 + c] = lo;
        *(bf16x4*)&ls[r * 68 + c + 4] = hi;
    }
    __syncthreads();
#pragma unroll
    for (int rep = 0; rep < 2; ++rep) {
        const int f = tid * 8 + rep * 2048;
        const int rn = f >> 6, ck = f & 63;
        bf16x8 v;
#pragma unroll
        for (int j = 0; j < 8; ++j) v[j] = (short)ls[(ck + j) * 68 + rn];
        *(bf16x8*)(dst + (size_t)(tc + rn) * R + tr + ck) = v;
    }
}

// ---------------------------------------------------------------------------
// GEMM: C[m][n] = sum_k A[m][k] * Bt[n][k] + bias[n].  M=8192, K=1024, bf16.
// MODE 0: N=3072, scatter to Q(scaled)[BH][T][D], K[BH][T][D], V^T[BH][D][T].
// MODE 1: N=1024, fp32 store to Of[M][N].
// ---------------------------------------------------------------------------
template <int MODE>
__global__ __launch_bounds__(256) void gemm_k(const u16* __restrict__ A, const u16* __restrict__ Bt,
                                              const float* __restrict__ bias,
                                              u16* __restrict__ Qo, u16* __restrict__ Ko,
                                              u16* __restrict__ Vo, float* __restrict__ Of) {
    constexpr int Kd = 1024;
    const int tid = threadIdx.x;
    const int lane = tid & 63, wave = tid >> 6;
    const int wm = wave >> 1, wn = wave & 1;
    const int lr = lane & 15, lg = lane >> 4;
    const int mt = blockIdx.x & 63;
    const int nt = blockIdx.x >> 6;
    const int mbase = mt << 7, nbase = nt << 7;
    __shared__ u16 As[128 * 32];
    __shared__ u16 Bs[128 * 32];
    f32x4 acc[4][4];
#pragma unroll
    for (int i = 0; i < 4; ++i)
#pragma unroll
        for (int j = 0; j < 4; ++j) acc[i][j] = {0.f, 0.f, 0.f, 0.f};

    for (int kb = 0; kb < Kd; kb += 32) {
        __syncthreads();
#pragma unroll
        for (int rep = 0; rep < 2; ++rep) {
            const int f = tid * 8 + rep * 2048;
            const int r = f >> 5, c = f & 31;
            __builtin_amdgcn_global_load_lds(
                (const __attribute__((address_space(1))) void*)(A + (size_t)(mbase + r) * Kd + kb + c),
                (__attribute__((address_space(3))) void*)(As + f), 16, 0, 0);
            __builtin_amdgcn_global_load_lds(
                (const __attribute__((address_space(1))) void*)(Bt + (size_t)(nbase + r) * Kd + kb + c),
                (__attribute__((address_space(3))) void*)(Bs + f), 16, 0, 0);
        }
        __syncthreads();
        bf16x8 af[4], bfr[4];
#pragma unroll
        for (int i = 0; i < 4; ++i)
            af[i] = *(const bf16x8*)&As[(wm * 64 + i * 16 + lr) * 32 + lg * 8];
#pragma unroll
        for (int j = 0; j < 4; ++j)
            bfr[j] = *(const bf16x8*)&Bs[(wn * 64 + j * 16 + lr) * 32 + lg * 8];
#pragma unroll
        for (int i = 0; i < 4; ++i)
#pragma unroll
            for (int j = 0; j < 4; ++j) acc[i][j] = MFMA16(af[i], bfr[j], acc[i][j]);
    }

    const float QSCALE = 0.1803368801111137f;  // 0.125 * log2(e), folded into Q
#pragma unroll
    for (int j = 0; j < 4; ++j) {
        const int n = nbase + wn * 64 + j * 16 + lr;
        const float bj = bias[n];
        if (MODE == 0) {
            const int three = n >> 10;
            const int h = (n >> 6) & 15;
            const int d = n & 63;
#pragma unroll
            for (int i = 0; i < 4; ++i) {
#pragma unroll
                for (int r = 0; r < 4; ++r) {
                    const int m = mbase + wm * 64 + i * 16 + lg * 4 + r;
                    const int b = m >> 11, t = m & 2047;
                    const int bh = (b << 4) + h;
                    const float val = acc[i][j][r] + bj;
                    if (three == 0)
                        Qo[(((size_t)bh << 11) + t) * 64 + d] = f2bf(val * QSCALE);
                    else if (three == 1)
                        Ko[(((size_t)bh << 11) + t) * 64 + d] = f2bf(val);
                    else
                        Vo[(((size_t)bh << 6) + d) * 2048 + t] = f2bf(val);
                }
            }
        } else {
#pragma unroll
            for (int i = 0; i < 4; ++i) {
#pragma unroll
                for (int r = 0; r < 4; ++r) {
                    const int m = mbase + wm * 64 + i * 16 + lg * 4 + r;
                    Of[((size_t)m << 10) + n] = acc[i][j][r] + bj;
                }
            }
        }
    }
}

// ---------------------------------------------------------------------------
// Causal flash attention, LDS-staged K/V (gemm_k-style 2-phase).
// Q,K: [BH][T][D] bf16 (Q pre-scaled), Vt: [BH][D][T] bf16, Aout: [B][T][C].
// grid (16, B*H), block 256 (4 waves). Block bx pairs q-tiles qb_hi=16+bx,
// qb_lo=15-bx; wave w owns 16 q rows of each (2 subtiles).
// Per kt, the block cooperatively stages K-tile[64][64] and Vt-tile[64][64]
// into LDS via global_load_lds (4 instr/thread -- replaces r0's 16 per-wave
// global_load_dwordx4; r2 showed redundant per-wave global K/V loads are the
// bottleneck: doubling them doubled time while VALUBusy FELL).
// LDS layout is chunk-XOR-swizzled (chunk c of row r stored at c^(r&7)):
// global_load_lds writes linearly, so the swizzle is applied by permuting the
// per-lane GLOBAL source chunk; ds_read_b128 applies the same XOR -> each
// rchunk value maps 8 lanes onto a disjoint 4-bank group = conflict-free
// (without this, all 16 lr lanes of an lg group hit one bank group: 16-way).
// ds_read addresses are kt-invariant (VALU savings vs per-kt 64-bit global
// addressing). K/V frags no longer persist in registers -> VGPR target <=128
// so 4 waves/SIMD co-reside (16 waves/CU; desync'd blocks cover the stage
// barriers). NO 2nd launch_bounds arg (acts as hard VGPR cap: r1 (256,4)->64,
// r3 (128,2)->128, both catastrophic spills).
// ---------------------------------------------------------------------------
__global__ __launch_bounds__(256) void flash_attn(const u16* __restrict__ Q, const u16* __restrict__ Kg,
                                                  const u16* __restrict__ Vt, u16* __restrict__ Aout) {
    const int tid = threadIdx.x;
    const int lane = tid & 63, wave = tid >> 6;  // wave 0..3
    const int lr = lane & 15, lg = lane >> 4;
    const int bx = blockIdx.x;   // 0..15
    const int bh = blockIdx.y;   // 0..63
    const int b = bh >> 4, h = bh & 15;
    const size_t base = (size_t)bh << 17;  // bh * 2048 * 64

    const int qb_hi = 16 + bx;
    const int qb_lo = 15 - bx;

    __shared__ u16 Ks[64 * 64];        // K tile  [kv_local][d], chunk-swizzled
    __shared__ u16 Vs[64 * 64];        // Vt tile [d][kv_local], chunk-swizzled
    __shared__ u16 Ps[4][16 * 72];     // per-wave P scratch

    // subtile q-bases: 0 = hi slice, 1 = lo slice (16 rows each)
    int qbase[2];
    qbase[0] = qb_hi * 64 + wave * 16;
    qbase[1] = qb_lo * 64 + wave * 16;

    bf16x8 qf[2][2];
#pragma unroll
    for (int st = 0; st < 2; ++st) {
        const u16* p = Q + base + (size_t)(qbase[st] + lr) * 64;
        qf[st][0] = *(const bf16x8*)(p + lg * 8);
        qf[st][1] = *(const bf16x8*)(p + 32 + lg * 8);
    }

    f32x4 o[2][4];
#pragma unroll
    for (int st = 0; st < 2; ++st)
#pragma unroll
        for (int dt = 0; dt < 4; ++dt) o[st][dt] = {0.f, 0.f, 0.f, 0.f};
    float m_[2] = {-INFINITY, -INFINITY};
    float l_[2] = {0.f, 0.f};

    // staging geometry (kt-invariant): thread stages 16B chunks.
    // dest (linear, as global_load_lds requires): byte f = (tid + rep*256)*16
    //   -> row = f>>7, chunk c = (f>>4)&7.
    // source chunk cc = c ^ (row&7)  (inverse of the read-side XOR).
    const int f0 = tid * 16;                 // rep 0 byte offset
    const int row0 = f0 >> 7, c0 = (f0 >> 4) & 7;
    const int cc0 = c0 ^ (row0 & 7);
    const int f1 = (tid + 256) * 16;         // rep 1
    const int row1 = f1 >> 7, c1 = (f1 >> 4) & 7;
    const int cc1 = c1 ^ (row1 & 7);

    const int xr = lr & 7;  // read-side XOR key

    auto process = [&](int st, bool diag, int kt) {
        // S^T[kv][q] = K * Q^T  (kv = kt*64 + rt*16 + lg*4 + reg, q = lr)
        f32x4 s[4];
#pragma unroll
        for (int rt = 0; rt < 4; ++rt) {
            const int krow = rt * 16 + lr;
            const bf16x8 k0 = *(const bf16x8*)&Ks[krow * 64 + ((lg) ^ xr) * 8];
            const bf16x8 k1 = *(const bf16x8*)&Ks[krow * 64 + ((lg + 4) ^ xr) * 8];
            f32x4 z = {0.f, 0.f, 0.f, 0.f};
            z = MFMA16(k0, qf[st][0], z);
            z = MFMA16(k1, qf[st][1], z);
            s[rt] = z;
        }
        if (diag) {
            const int q_glob = qbase[st] + lr;
#pragma unroll
            for (int rt = 0; rt < 4; ++rt)
#pragma unroll
                for (int r = 0; r < 4; ++r) {
                    const int kv = kt * 64 + rt * 16 + lg * 4 + r;
                    if (kv > q_glob) s[rt][r] = -INFINITY;
                }
        }
        float rmax = -INFINITY;
#pragma unroll
        for (int rt = 0; rt < 4; ++rt)
#pragma unroll
            for (int r = 0; r < 4; ++r) rmax = fmaxf(rmax, s[rt][r]);
        rmax = fmaxf(rmax, __shfl_xor(rmax, 16));
        rmax = fmaxf(rmax, __shfl_xor(rmax, 32));
        const float m_new = fmaxf(m_[st], rmax);
        const float alpha = exp2f(m_[st] - m_new);
        float rsum = 0.f;
#pragma unroll
        for (int rt = 0; rt < 4; ++rt)
#pragma unroll
            for (int r = 0; r < 4; ++r) {
                const float p = exp2f(s[rt][r] - m_new);
                s[rt][r] = p;
                rsum += p;
            }
        rsum += __shfl_xor(rsum, 16);
        rsum += __shfl_xor(rsum, 32);
        l_[st] = l_[st] * alpha + rsum;
        m_[st] = m_new;

        // P (C-layout) -> LDS -> A-layout frags
        u16* psb = &Ps[wave][0];
#pragma unroll
        for (int rt = 0; rt < 4; ++rt) {
            bf16x4 pk;
#pragma unroll
            for (int r = 0; r < 4; ++r) pk[r] = (short)f2bf_fast(s[rt][r]);
            *(bf16x4*)&psb[lr * 72 + rt * 16 + lg * 4] = pk;
        }
        float aq[4];
#pragma unroll
        for (int r = 0; r < 4; ++r) aq[r] = __shfl(alpha, (lane & 48) + lg * 4 + r);
#pragma unroll
        for (int dt = 0; dt < 4; ++dt)
#pragma unroll
            for (int r = 0; r < 4; ++r) o[st][dt][r] *= aq[r];

        const bf16x8 pf0 = *(const bf16x8*)&psb[lr * 72 + lg * 8];
        const bf16x8 pf1 = *(const bf16x8*)&psb[lr * 72 + 32 + lg * 8];
#pragma unroll
        for (int dt = 0; dt < 4; ++dt) {
            const int vrow = dt * 16 + lr;
            const bf16x8 v0 = *(const bf16x8*)&Vs[vrow * 64 + ((lg) ^ xr) * 8];
            const bf16x8 v1 = *(const bf16x8*)&Vs[vrow * 64 + ((lg + 4) ^ xr) * 8];
            o[st][dt] = MFMA16(pf0, v0, o[st][dt]);
            o[st][dt] = MFMA16(pf1, v1, o[st][dt]);
        }
    };

    for (int kt = 0; kt <= qb_hi; ++kt) {
        __syncthreads();  // previous compute done before overwrite
        // stage K tile: global row kt*64+row, source chunk cc (pre-swizzled)
        __builtin_amdgcn_global_load_lds(
            (const __attribute__((address_space(1))) void*)(Kg + base + (size_t)(kt * 64 + row0) * 64 + cc0 * 8),
            (__attribute__((address_space(3))) void*)(Ks + tid * 8), 16, 0, 0);
        __builtin_amdgcn_global_load_lds(
            (const __attribute__((address_space(1))) void*)(Kg + base + (size_t)(kt * 64 + row1) * 64 + cc1 * 8),
            (__attribute__((address_space(3))) void*)(Ks + 2048 + tid * 8), 16, 0, 0);
        // stage Vt tile: global row d=row, cols kt*64 + chunk cc
        __builtin_amdgcn_global_load_lds(
            (const __attribute__((address_space(1))) void*)(Vt + base + (size_t)row0 * 2048 + kt * 64 + cc0 * 8),
            (__attribute__((address_space(3))) void*)(Vs + tid * 8), 16, 0, 0);
        __builtin_amdgcn_global_load_lds(
            (const __attribute__((address_space(1))) void*)(Vt + base + (size_t)row1 * 2048 + kt * 64 + cc1 * 8),
            (__attribute__((address_space(3))) void*)(Vs + 2048 + tid * 8), 16, 0, 0);
        __syncthreads();  // drains vmcnt (compiler emits waitcnt before barrier)

        process(0, kt == qb_hi, kt);
        if (kt <= qb_lo) process(1, kt == qb_lo, kt);
    }

#pragma unroll
    for (int st = 0; st < 2; ++st) {
        const float linv = 1.f / l_[st];
        float lq[4];
#pragma unroll
        for (int r = 0; r < 4; ++r) lq[r] = __shfl(linv, (lane & 48) + lg * 4 + r);
#pragma unroll
        for (int dt = 0; dt < 4; ++dt)
#pragma unroll
            for (int r = 0; r < 4; ++r) {
                const int t = qbase[st] + lg * 4 + r;
                Aout[(((size_t)(b << 11) + t) << 10) + h * 64 + dt * 16 + lr] =
                    f2bf(o[st][dt][r] * lq[r]);
            }
    }
}

// ---------------------------------------------------------------------------
extern "C" void kernel_launch(void* const* d_in, const int* in_sizes, int n_in,
                              void* d_out, int out_size, void* d_ws, size_t ws_size,
                              hipStream_t stream) {
    (void)in_sizes; (void)n_in; (void)out_size; (void)ws_size;
    const float* x    = (const float*)d_in[0];
    const float* Wqkv = (const float*)d_in[2];
    const float* bqkv = (const float*)d_in[3];
    const float* Wout = (const float*)d_in[4];
    const float* bout = (const float*)d_in[5];
    float* out = (float*)d_out;

    char* ws = (char*)d_ws;
    u16* WqkvT = (u16*)(ws);                    //  6 MB: [3072][1024] bf16
    u16* WoutT = (u16*)(ws + 6291456);          //  2 MB: [1024][1024] bf16
    u16* xb    = (u16*)(ws + 8388608);          // 16 MB: [8192][1024] bf16
    u16* Qb    = (u16*)(ws + 25165824);         // 16 MB: [BH][T][D]
    u16* Kb    = (u16*)(ws + 41943040);         // 16 MB: [BH][T][D]
    u16* Vtb   = (u16*)(ws + 58720256);         // 16 MB: [BH][D][T]
    u16* Ab    = (u16*)(ws + 75497472);         // 16 MB: [B][T][C]

    castk<<<dim3(4096), 256, 0, stream>>>(x, xb);
    tkern<<<dim3(16 * 48), 256, 0, stream>>>(Wqkv, WqkvT, 1024, 3072);
    tkern<<<dim3(16 * 16), 256, 0, stream>>>(Wout, WoutT, 1024, 1024);
    gemm_k<0><<<dim3(64 * 24), 256, 0, stream>>>(xb, WqkvT, bqkv, Qb, Kb, Vtb, nullptr);
    flash_attn<<<dim3(16, 64), 256, 0, stream>>>(Qb, Kb, Vtb, Ab);
    gemm_k<1><<<dim3(64 * 8), 256, 0, stream>>>(Ab, WoutT, bout, nullptr, nullptr, nullptr, out);
}

// Round 6
// 320.818 us; speedup vs baseline: 1.8393x; 1.0258x over previous
//
#include <hip/hip_runtime.h>

typedef unsigned short u16;
typedef __attribute__((ext_vector_type(8))) short bf16x8;
typedef __attribute__((ext_vector_type(4))) short bf16x4;
typedef __attribute__((ext_vector_type(4))) float f32x4;

#define MFMA16(a, b, c) __builtin_amdgcn_mfma_f32_16x16x32_bf16(a, b, c, 0, 0, 0)

__device__ __forceinline__ u16 f2bf(float x) {
    unsigned u = __float_as_uint(x);
    return (u16)((u + 0x7fffu + ((u >> 16) & 1u)) >> 16);
}
__device__ __forceinline__ u16 f2bf_fast(float x) {  // round-half-up (P matrix only)
    return (u16)((__float_as_uint(x) + 0x8000u) >> 16);
}

// ---------------------------------------------------------------------------
// fp32 -> bf16 flat cast. n must be a multiple of 8*256.
// ---------------------------------------------------------------------------
__global__ __launch_bounds__(256) void castk(const float* __restrict__ src, u16* __restrict__ dst) {
    const int i = (blockIdx.x * 256 + threadIdx.x) * 8;
    float4 a = *(const float4*)(src + i);
    float4 b = *(const float4*)(src + i + 4);
    bf16x8 v;
    v[0] = (short)f2bf(a.x); v[1] = (short)f2bf(a.y);
    v[2] = (short)f2bf(a.z); v[3] = (short)f2bf(a.w);
    v[4] = (short)f2bf(b.x); v[5] = (short)f2bf(b.y);
    v[6] = (short)f2bf(b.z); v[7] = (short)f2bf(b.w);
    *(bf16x8*)(dst + i) = v;
}

// ---------------------------------------------------------------------------
// fp32 src[r][c] -> bf16 dst[c][r], 64x64 LDS tiles. grid R/64*C/64, block 256
// ---------------------------------------------------------------------------
__global__ __launch_bounds__(256) void tkern(const float* __restrict__ src, u16* __restrict__ dst,
                                             int R, int C) {
    const int tC = C >> 6;
    const int tr = (blockIdx.x / tC) << 6;
    const int tc = (blockIdx.x % tC) << 6;
    __shared__ u16 ls[64 * 68];
    const int tid = threadIdx.x;
#pragma unroll
    for (int rep = 0; rep < 2; ++rep) {
        const int f = tid * 8 + rep * 2048;
        const int r = f >> 6, c = f & 63;
        float4 a = *(const float4*)(src + (size_t)(tr + r) * C + tc + c);
        float4 b = *(const float4*)(src + (size_t)(tr + r) * C + tc + c + 4);
        bf16x4 lo, hi;
        lo[0] = (short)f2bf(a.x); lo[1] = (short)f2bf(a.y);
        lo[2] = (short)f2bf(a.z); lo[3] = (short)f2bf(a.w);
        hi[0] = (short)f2bf(b.x); hi[1] = (short)f2bf(b.y);
        hi[2] = (short)f2bf(b.z); hi[3] = (short)f2bf(b.w);
        *(bf16x4*)&ls[r * 68 + c] = lo;
        *(bf16x4*)&ls[r * 68 + c + 4] = hi;
    }
    __syncthreads();
#pragma unroll
    for (int rep = 0; rep < 2; ++rep) {
        const int f = tid * 8 + rep * 2048;
        const int rn = f >> 6, ck = f & 63;
        bf16x8 v;
#pragma unroll
        for (int j = 0; j < 8; ++j) v[j] = (short)ls[(ck + j) * 68 + rn];
        *(bf16x8*)(dst + (size_t)(tc + rn) * R + tr + ck) = v;
    }
}

// ---------------------------------------------------------------------------
// GEMM: C[m][n] = sum_k A[m][k] * Bt[n][k] + bias[n].  M=8192, K=1024, bf16.
// MODE 0: N=3072, scatter to Q(scaled)[BH][T][D], K[BH][T][D], V^T[BH][D][T].
// MODE 1: N=1024, fp32 store to Of[M][N].
// ---------------------------------------------------------------------------
template <int MODE>
__global__ __launch_bounds__(256) void gemm_k(const u16* __restrict__ A, const u16* __restrict__ Bt,
                                              const float* __restrict__ bias,
                                              u16* __restrict__ Qo, u16* __restrict__ Ko,
                                              u16* __restrict__ Vo, float* __restrict__ Of) {
    constexpr int Kd = 1024;
    const int tid = threadIdx.x;
    const int lane = tid & 63, wave = tid >> 6;
    const int wm = wave >> 1, wn = wave & 1;
    const int lr = lane & 15, lg = lane >> 4;
    const int mt = blockIdx.x & 63;
    const int nt = blockIdx.x >> 6;
    const int mbase = mt << 7, nbase = nt << 7;
    __shared__ u16 As[128 * 32];
    __shared__ u16 Bs[128 * 32];
    f32x4 acc[4][4];
#pragma unroll
    for (int i = 0; i < 4; ++i)
#pragma unroll
        for (int j = 0; j < 4; ++j) acc[i][j] = {0.f, 0.f, 0.f, 0.f};

    for (int kb = 0; kb < Kd; kb += 32) {
        __syncthreads();
#pragma unroll
        for (int rep = 0; rep < 2; ++rep) {
            const int f = tid * 8 + rep * 2048;
            const int r = f >> 5, c = f & 31;
            __builtin_amdgcn_global_load_lds(
                (const __attribute__((address_space(1))) void*)(A + (size_t)(mbase + r) * Kd + kb + c),
                (__attribute__((address_space(3))) void*)(As + f), 16, 0, 0);
            __builtin_amdgcn_global_load_lds(
                (const __attribute__((address_space(1))) void*)(Bt + (size_t)(nbase + r) * Kd + kb + c),
                (__attribute__((address_space(3))) void*)(Bs + f), 16, 0, 0);
        }
        __syncthreads();
        bf16x8 af[4], bfr[4];
#pragma unroll
        for (int i = 0; i < 4; ++i)
            af[i] = *(const bf16x8*)&As[(wm * 64 + i * 16 + lr) * 32 + lg * 8];
#pragma unroll
        for (int j = 0; j < 4; ++j)
            bfr[j] = *(const bf16x8*)&Bs[(wn * 64 + j * 16 + lr) * 32 + lg * 8];
#pragma unroll
        for (int i = 0; i < 4; ++i)
#pragma unroll
            for (int j = 0; j < 4; ++j) acc[i][j] = MFMA16(af[i], bfr[j], acc[i][j]);
    }

    const float QSCALE = 0.1803368801111137f;  // 0.125 * log2(e), folded into Q
#pragma unroll
    for (int j = 0; j < 4; ++j) {
        const int n = nbase + wn * 64 + j * 16 + lr;
        const float bj = bias[n];
        if (MODE == 0) {
            const int three = n >> 10;
            const int h = (n >> 6) & 15;
            const int d = n & 63;
#pragma unroll
            for (int i = 0; i < 4; ++i) {
#pragma unroll
                for (int r = 0; r < 4; ++r) {
                    const int m = mbase + wm * 64 + i * 16 + lg * 4 + r;
                    const int b = m >> 11, t = m & 2047;
                    const int bh = (b << 4) + h;
                    const float val = acc[i][j][r] + bj;
                    if (three == 0)
                        Qo[(((size_t)bh << 11) + t) * 64 + d] = f2bf(val * QSCALE);
                    else if (three == 1)
                        Ko[(((size_t)bh << 11) + t) * 64 + d] = f2bf(val);
                    else
                        Vo[(((size_t)bh << 6) + d) * 2048 + t] = f2bf(val);
                }
            }
        } else {
#pragma unroll
            for (int i = 0; i < 4; ++i) {
#pragma unroll
                for (int r = 0; r < 4; ++r) {
                    const int m = mbase + wm * 64 + i * 16 + lg * 4 + r;
                    Of[((size_t)m << 10) + n] = acc[i][j][r] + bj;
                }
            }
        }
    }
}

// ---------------------------------------------------------------------------
// Causal flash attention, LDS-staged K/V, DOUBLE-BUFFERED (T3 minimal 2-phase).
// Q,K: [BH][T][D] bf16 (Q pre-scaled), Vt: [BH][D][T] bf16, Aout: [B][T][C].
// 1D grid 1024 with XCD swizzle: swz=(bid&7)*128+(bid>>3) -> each XCD owns 8
// bh (K/V working set 4MB = one XCD L2), all 16 q-blocks of a bh on one XCD.
// Block bx pairs q-tiles qb_hi=16+bx, qb_lo=15-bx; wave w owns 16 q rows of
// each. Per kt: barrier -> issue stage(buf^1, kt+1) -> compute(buf, kt).
// The vmcnt(0) the compiler emits before the NEXT barrier then waits on loads
// issued a full compute phase earlier (~0 stall), and there is ONE barrier
// per kt (r5 had two + a fully exposed stage round-trip every kt: MfmaUtil
// 11.5, VALU 52, waves parked at the drain).
// LDS budget: Ks 2x8KB + Vs 2x8KB + Ps 8KB = 40960 B = exactly 163840/4 ->
// keeps 4 blocks/CU. Ps is chunk-XOR-swizzled ([16 rows][8 chunks of 16B],
// phys_chunk = logical_chunk ^ (lr&7)): write 8B x4 and read b128 both <=2-way.
// K/V tiles chunk-XOR-swizzled via pre-swizzled GLOBAL source (rule 21).
// NO 2nd launch_bounds arg (hard VGPR cap: r1 (256,4)->64, r3 (128,2)->128,
// both catastrophic spills).
// ---------------------------------------------------------------------------
__global__ __launch_bounds__(256) void flash_attn(const u16* __restrict__ Q, const u16* __restrict__ Kg,
                                                  const u16* __restrict__ Vt, u16* __restrict__ Aout) {
    const int tid = threadIdx.x;
    const int lane = tid & 63, wave = tid >> 6;  // wave 0..3
    const int lr = lane & 15, lg = lane >> 4;
    const int bid = blockIdx.x;                  // 0..1023
    const int swz = (bid & 7) * 128 + (bid >> 3);
    const int bh = swz >> 4;     // 0..63
    const int bx = swz & 15;     // 0..15
    const int b = bh >> 4, h = bh & 15;
    const size_t base = (size_t)bh << 17;  // bh * 2048 * 64

    const int qb_hi = 16 + bx;
    const int qb_lo = 15 - bx;

    __shared__ u16 Ks[2][64 * 64];     // K tile  [kv_local][d], chunk-swizzled
    __shared__ u16 Vs[2][64 * 64];     // Vt tile [d][kv_local], chunk-swizzled
    __shared__ u16 Ps[4][16 * 64];     // per-wave P scratch, chunk-XOR-swizzled

    // subtile q-bases: 0 = hi slice, 1 = lo slice (16 rows each)
    int qbase[2];
    qbase[0] = qb_hi * 64 + wave * 16;
    qbase[1] = qb_lo * 64 + wave * 16;

    bf16x8 qf[2][2];
#pragma unroll
    for (int st = 0; st < 2; ++st) {
        const u16* p = Q + base + (size_t)(qbase[st] + lr) * 64;
        qf[st][0] = *(const bf16x8*)(p + lg * 8);
        qf[st][1] = *(const bf16x8*)(p + 32 + lg * 8);
    }

    f32x4 o[2][4];
#pragma unroll
    for (int st = 0; st < 2; ++st)
#pragma unroll
        for (int dt = 0; dt < 4; ++dt) o[st][dt] = {0.f, 0.f, 0.f, 0.f};
    float m_[2] = {-INFINITY, -INFINITY};
    float l_[2] = {0.f, 0.f};

    // staging geometry (kt-invariant): thread stages 16B chunks.
    // dest (linear, as global_load_lds requires): byte f = (tid + rep*256)*16
    //   -> row = f>>7, chunk c = (f>>4)&7.  source chunk cc = c ^ (row&7).
    const int f0 = tid * 16;                 // rep 0 byte offset
    const int row0 = f0 >> 7, c0 = (f0 >> 4) & 7;
    const int cc0 = c0 ^ (row0 & 7);
    const int f1 = (tid + 256) * 16;         // rep 1
    const int row1 = f1 >> 7, c1 = (f1 >> 4) & 7;
    const int cc1 = c1 ^ (row1 & 7);

    const int xr = lr & 7;  // read-side XOR key

    auto stage = [&](int sel, int kt) {
        const size_t krow = base + (size_t)(kt * 64) * 64;
        __builtin_amdgcn_global_load_lds(
            (const __attribute__((address_space(1))) void*)(Kg + krow + (size_t)row0 * 64 + cc0 * 8),
            (__attribute__((address_space(3))) void*)(&Ks[sel][tid * 8]), 16, 0, 0);
        __builtin_amdgcn_global_load_lds(
            (const __attribute__((address_space(1))) void*)(Kg + krow + (size_t)row1 * 64 + cc1 * 8),
            (__attribute__((address_space(3))) void*)(&Ks[sel][2048 + tid * 8]), 16, 0, 0);
        __builtin_amdgcn_global_load_lds(
            (const __attribute__((address_space(1))) void*)(Vt + base + (size_t)row0 * 2048 + kt * 64 + cc0 * 8),
            (__attribute__((address_space(3))) void*)(&Vs[sel][tid * 8]), 16, 0, 0);
        __builtin_amdgcn_global_load_lds(
            (const __attribute__((address_space(1))) void*)(Vt + base + (size_t)row1 * 2048 + kt * 64 + cc1 * 8),
            (__attribute__((address_space(3))) void*)(&Vs[sel][2048 + tid * 8]), 16, 0, 0);
    };

    auto process = [&](int sel, int st, bool diag, int kt) {
        // S^T[kv][q] = K * Q^T  (kv = kt*64 + rt*16 + lg*4 + reg, q = lr)
        f32x4 s[4];
#pragma unroll
        for (int rt = 0; rt < 4; ++rt) {
            const int krow = rt * 16 + lr;
            const bf16x8 k0 = *(const bf16x8*)&Ks[sel][krow * 64 + ((lg) ^ xr) * 8];
            const bf16x8 k1 = *(const bf16x8*)&Ks[sel][krow * 64 + ((lg + 4) ^ xr) * 8];
            f32x4 z = {0.f, 0.f, 0.f, 0.f};
            z = MFMA16(k0, qf[st][0], z);
            z = MFMA16(k1, qf[st][1], z);
            s[rt] = z;
        }
        if (diag) {
            const int q_glob = qbase[st] + lr;
#pragma unroll
            for (int rt = 0; rt < 4; ++rt)
#pragma unroll
                for (int r = 0; r < 4; ++r) {
                    const int kv = kt * 64 + rt * 16 + lg * 4 + r;
                    if (kv > q_glob) s[rt][r] = -INFINITY;
                }
        }
        float rmax = -INFINITY;
#pragma unroll
        for (int rt = 0; rt < 4; ++rt)
#pragma unroll
            for (int r = 0; r < 4; ++r) rmax = fmaxf(rmax, s[rt][r]);
        rmax = fmaxf(rmax, __shfl_xor(rmax, 16));
        rmax = fmaxf(rmax, __shfl_xor(rmax, 32));
        const float m_new = fmaxf(m_[st], rmax);
        const float alpha = exp2f(m_[st] - m_new);
        float rsum = 0.f;
#pragma unroll
        for (int rt = 0; rt < 4; ++rt)
#pragma unroll
            for (int r = 0; r < 4; ++r) {
                const float p = exp2f(s[rt][r] - m_new);
                s[rt][r] = p;
                rsum += p;
            }
        rsum += __shfl_xor(rsum, 16);
        rsum += __shfl_xor(rsum, 32);
        l_[st] = l_[st] * alpha + rsum;
        m_[st] = m_new;

        // P (C-layout) -> LDS (XOR-swizzled rows of 8x16B chunks) -> A-frags
        u16* psb = &Ps[wave][0];
#pragma unroll
        for (int rt = 0; rt < 4; ++rt) {
            bf16x4 pk;
#pragma unroll
            for (int r = 0; r < 4; ++r) pk[r] = (short)f2bf_fast(s[rt][r]);
            *(bf16x4*)&psb[lr * 64 + (((rt * 2 + (lg >> 1)) ^ xr) << 3) + ((lg & 1) << 2)] = pk;
        }
        float aq[4];
#pragma unroll
        for (int r = 0; r < 4; ++r) aq[r] = __shfl(alpha, (lane & 48) + lg * 4 + r);
#pragma unroll
        for (int dt = 0; dt < 4; ++dt)
#pragma unroll
            for (int r = 0; r < 4; ++r) o[st][dt][r] *= aq[r];

        const bf16x8 pf0 = *(const bf16x8*)&psb[lr * 64 + ((lg ^ xr) << 3)];
        const bf16x8 pf1 = *(const bf16x8*)&psb[lr * 64 + (((4 + lg) ^ xr) << 3)];
#pragma unroll
        for (int dt = 0; dt < 4; ++dt) {
            const int vrow = dt * 16 + lr;
            const bf16x8 v0 = *(const bf16x8*)&Vs[sel][vrow * 64 + ((lg) ^ xr) * 8];
            const bf16x8 v1 = *(const bf16x8*)&Vs[sel][vrow * 64 + ((lg + 4) ^ xr) * 8];
            o[st][dt] = MFMA16(pf0, v0, o[st][dt]);
            o[st][dt] = MFMA16(pf1, v1, o[st][dt]);
        }
    };

    stage(0, 0);
    for (int kt = 0; kt <= qb_hi; ++kt) {
        const int cur = kt & 1;
        __syncthreads();  // per-wave vmcnt(0) drain before barrier -> buf[cur]
                          // staged; also: all waves done reading buf[cur^1]
        if (kt < qb_hi) stage(cur ^ 1, kt + 1);
        process(cur, 0, kt == qb_hi, kt);
        if (kt <= qb_lo) process(cur, 1, kt == qb_lo, kt);
    }

#pragma unroll
    for (int st = 0; st < 2; ++st) {
        const float linv = 1.f / l_[st];
        float lq[4];
#pragma unroll
        for (int r = 0; r < 4; ++r) lq[r] = __shfl(linv, (lane & 48) + lg * 4 + r);
#pragma unroll
        for (int dt = 0; dt < 4; ++dt)
#pragma unroll
            for (int r = 0; r < 4; ++r) {
                const int t = qbase[st] + lg * 4 + r;
                Aout[(((size_t)(b << 11) + t) << 10) + h * 64 + dt * 16 + lr] =
                    f2bf(o[st][dt][r] * lq[r]);
            }
    }
}

// ---------------------------------------------------------------------------
extern "C" void kernel_launch(void* const* d_in, const int* in_sizes, int n_in,
                              void* d_out, int out_size, void* d_ws, size_t ws_size,
                              hipStream_t stream) {
    (void)in_sizes; (void)n_in; (void)out_size; (void)ws_size;
    const float* x    = (const float*)d_in[0];
    const float* Wqkv = (const float*)d_in[2];
    const float* bqkv = (const float*)d_in[3];
    const float* Wout = (const float*)d_in[4];
    const float* bout = (const float*)d_in[5];
    float* out = (float*)d_out;

    char* ws = (char*)d_ws;
    u16* WqkvT = (u16*)(ws);                    //  6 MB: [3072][1024] bf16
    u16* WoutT = (u16*)(ws + 6291456);          //  2 MB: [1024][1024] bf16
    u16* xb    = (u16*)(ws + 8388608);          // 16 MB: [8192][1024] bf16
    u16* Qb    = (u16*)(ws + 25165824);         // 16 MB: [BH][T][D]
    u16* Kb    = (u16*)(ws + 41943040);         // 16 MB: [BH][T][D]
    u16* Vtb   = (u16*)(ws + 58720256);         // 16 MB: [BH][D][T]
    u16* Ab    = (u16*)(ws + 75497472);         // 16 MB: [B][T][C]

    castk<<<dim3(4096), 256, 0, stream>>>(x, xb);
    tkern<<<dim3(16 * 48), 256, 0, stream>>>(Wqkv, WqkvT, 1024, 3072);
    tkern<<<dim3(16 * 16), 256, 0, stream>>>(Wout, WoutT, 1024, 1024);
    gemm_k<0><<<dim3(64 * 24), 256, 0, stream>>>(xb, WqkvT, bqkv, Qb, Kb, Vtb, nullptr);
    flash_attn<<<dim3(1024), 256, 0, stream>>>(Qb, Kb, Vtb, Ab);
    gemm_k<1><<<dim3(64 * 8), 256, 0, stream>>>(Ab, WoutT, bout, nullptr, nullptr, nullptr, out);
}